// Round 8
// baseline (99.952 us; speedup 1.0000x reference)
//
#include <hip/hip_runtime.h>
#include <hip/hip_bf16.h>

#define SEQ    2048
#define DMODEL 1024
#define NHEADS 16
#define HD     64
#define CS     64
#define NC     (SEQ / CS)
#define STSZ   (HD * HD + HD)   // 4160 f32: KVT[64][64] + ksum[64]
#define EPS_LA 1e-5f
#define LP     72               // padded LDS row stride (bf16 elems)

typedef __attribute__((ext_vector_type(8))) short  bf16x8;
typedef __attribute__((ext_vector_type(8))) unsigned short ushort8;
typedef __attribute__((ext_vector_type(4))) float  f32x4;

__device__ __forceinline__ void gload_lds16(const void* g, void* l) {
  __builtin_amdgcn_global_load_lds(
      (const __attribute__((address_space(1))) void*)g,
      (__attribute__((address_space(3))) void*)l, 16, 0, 0);
}

__device__ __forceinline__ ushort f2bf(float x) {
  __hip_bfloat16 h = __float2bfloat16(x);
  return __builtin_bit_cast(ushort, h);
}
__device__ __forceinline__ float bf2f(ushort u) {
  unsigned int v = ((unsigned int)u) << 16;
  return __builtin_bit_cast(float, v);
}

// ---------------------------------------------------------------------------
// x (f32) -> bf16 elementwise
// ---------------------------------------------------------------------------
__global__ __launch_bounds__(256) void conv_bf16(
    const float* __restrict__ src, ushort* __restrict__ dst) {
  const int i = blockIdx.x * 256 + threadIdx.x;
  float4 v = *(const float4*)(src + (size_t)i * 4);
  ushort4 o;
  o.x = f2bf(v.x); o.y = f2bf(v.y); o.z = f2bf(v.z); o.w = f2bf(v.w);
  *(ushort4*)(dst + (size_t)i * 4) = o;
}

// ---------------------------------------------------------------------------
// src [R][Ncols] f32 -> dst [Ncols][R] bf16
// ---------------------------------------------------------------------------
__global__ __launch_bounds__(256) void transpose_to_bf16(
    const float* __restrict__ src, ushort* __restrict__ dst, int R, int Ncols) {
  __shared__ float t[64][65];
  const int r0 = blockIdx.y * 64, c0 = blockIdx.x * 64;
  const int tid = threadIdx.x;
  const int lr = tid >> 2;
  const int lc = (tid & 3) * 16;
  const float* sp = src + (size_t)(r0 + lr) * Ncols + c0 + lc;
  #pragma unroll
  for (int j = 0; j < 4; ++j) {
    float4 v = *(const float4*)(sp + j * 4);
    t[lr][lc + j * 4 + 0] = v.x;
    t[lr][lc + j * 4 + 1] = v.y;
    t[lr][lc + j * 4 + 2] = v.z;
    t[lr][lc + j * 4 + 3] = v.w;
  }
  __syncthreads();
  ushort out[16];
  #pragma unroll
  for (int j = 0; j < 16; ++j)
    out[j] = f2bf(t[lc + j][lr]);
  ushort* dp = dst + (size_t)(c0 + lr) * R + r0 + lc;
  *(uint4*)dp = *(const uint4*)&out[0];
  *(uint4*)(dp + 8) = *(const uint4*)&out[8];
}

// ---------------------------------------------------------------------------
// 256x256 8-wave phased GEMM (T2 swizzle + T3-style phases + T5 setprio).
// BK=64, 512 threads (2M x 4N waves), dbuf LDS 128 KiB, 4 phases/K-tile:
//   phase = {12x ds_read_b128 frags; issue 1A+1B stage-quarter of next tile;
//            raw s_barrier; setprio(1); 16 MFMA; setprio(0)}
// One __syncthreads (full drain) per K-tile. Stage loads get 1-4 phases of
// MFMA cover instead of a per-half drain. LDS XOR-swizzle identical to the
// proven round-7 scheme (pre-swizzled global source, swizzled read).
// ---------------------------------------------------------------------------
template <bool OUT_BF16>
__global__ __launch_bounds__(512, 2) void gemm_8ph(
    const ushort* __restrict__ A, const ushort* __restrict__ Bt,
    void* __restrict__ Cv, int M, int N, int K, int relu_limit, int nbx) {
  __shared__ ushort Asm[2][256 * 64];
  __shared__ ushort Bsm[2][256 * 64];

  // XCD-aware bijective remap (gridDim.x % 8 == 0)
  int wg = blockIdx.x;
  const int cpx = gridDim.x >> 3;
  wg = (wg & 7) * cpx + (wg >> 3);
  const int bx = wg % nbx;
  const int by = wg / nbx;
  const int brow = by * 256;
  const int bcol = bx * 256;

  const int tid  = threadIdx.x;
  const int lane = tid & 63;
  const int w    = tid >> 6;       // 0..7
  const int wm   = w >> 2;         // 0..1  (M half)
  const int wn   = w & 3;          // 0..3  (N quarter)
  const int l15  = lane & 15;
  const int khi  = (lane >> 4) * 8;
  const int r8   = lane >> 3;      // 0..7 row-in-8
  const int acol = ((lane & 7) ^ r8) * 8;   // pre-swizzled global source col

  // staging: chunk (u,w) covers rows u*64 + w*8 + r8 (u = quarter 0..3)
  const ushort* Ag = A  + (size_t)(brow + w * 8 + r8) * K + acol;
  const ushort* Bg = Bt + (size_t)(bcol + w * 8 + r8) * K + acol;

  f32x4 acc[8][4];
  #pragma unroll
  for (int i = 0; i < 8; ++i)
    #pragma unroll
    for (int j = 0; j < 4; ++j) acc[i][j] = (f32x4)0.f;

  // prologue: stage K-tile 0 into buf 0 (4 quarters x {A,B})
  #pragma unroll
  for (int u = 0; u < 4; ++u) {
    gload_lds16(Ag + (size_t)u * 64 * K, &Asm[0][(u * 8 + w) * 512]);
    gload_lds16(Bg + (size_t)u * 64 * K, &Bsm[0][(u * 8 + w) * 512]);
  }
  __syncthreads();

  const int NT = K >> 6;
  int cur = 0;
  for (int kt = 0; kt < NT; ++kt) {
    const ushort* An = Ag + (size_t)(kt + 1) * 64;
    const ushort* Bn = Bg + (size_t)(kt + 1) * 64;
    const bool pf = (kt + 1 < NT);
    #pragma unroll
    for (int ph = 0; ph < 4; ++ph) {
      const int rh = ph >> 1, ch = ph & 1;
      // ---- ds_read this phase's fragments (compiler inserts lgkm waits) ----
      bf16x8 af[4][2], bfr[2][2];
      #pragma unroll
      for (int i = 0; i < 4; ++i) {
        const int r = wm * 128 + (rh * 4 + i) * 16 + l15;
        #pragma unroll
        for (int ks = 0; ks < 2; ++ks)
          af[i][ks] = *(const bf16x8*)
              &Asm[cur][r * 64 + ((ks * 32 + khi) ^ ((r & 7) << 3))];
      }
      #pragma unroll
      for (int j = 0; j < 2; ++j) {
        const int rn = wn * 64 + (ch * 2 + j) * 16 + l15;
        #pragma unroll
        for (int ks = 0; ks < 2; ++ks)
          bfr[j][ks] = *(const bf16x8*)
              &Bsm[cur][rn * 64 + ((ks * 32 + khi) ^ ((rn & 7) << 3))];
      }
      // ---- issue one stage quarter of the NEXT tile (flies under MFMA) ----
      if (pf) {
        gload_lds16(An + (size_t)ph * 64 * K, &Asm[cur ^ 1][(ph * 8 + w) * 512]);
        gload_lds16(Bn + (size_t)ph * 64 * K, &Bsm[cur ^ 1][(ph * 8 + w) * 512]);
      }
      __builtin_amdgcn_s_barrier();   // raw: aligns waves, no counter drain
      __builtin_amdgcn_s_setprio(1);
      #pragma unroll
      for (int i = 0; i < 4; ++i)
        #pragma unroll
        for (int j = 0; j < 2; ++j)
          #pragma unroll
          for (int ks = 0; ks < 2; ++ks)
            acc[rh * 4 + i][ch * 2 + j] = __builtin_amdgcn_mfma_f32_16x16x32_bf16(
                af[i][ks], bfr[j][ks], acc[rh * 4 + i][ch * 2 + j], 0, 0, 0);
      __builtin_amdgcn_s_setprio(0);
    }
    __syncthreads();   // full drain: next tile's staging complete
    cur ^= 1;
  }

  // epilogue
  #pragma unroll
  for (int fr = 0; fr < 8; ++fr) {
    #pragma unroll
    for (int fc = 0; fc < 4; ++fc) {
      const int r0  = brow + wm * 128 + fr * 16 + (lane >> 4) * 4;
      const int col = bcol + wn * 64 + fc * 16 + l15;
      const bool rl = col < relu_limit;
      #pragma unroll
      for (int i = 0; i < 4; ++i) {
        float v = acc[fr][fc][i];
        if (rl) v = fmaxf(v, 0.f);
        if (OUT_BF16)
          ((ushort*)Cv)[(size_t)(r0 + i) * N + col] = f2bf(v);
        else
          ((float*)Cv)[(size_t)(r0 + i) * N + col] = v;
      }
    }
  }
}

// ---------------------------------------------------------------------------
// 128x128 2-phase swizzled GEMM (round-7, proven) — used for GEMM2.
// ---------------------------------------------------------------------------
template <bool OUT_BF16>
__global__ __launch_bounds__(256) void gemm_swz(
    const ushort* __restrict__ A, const ushort* __restrict__ Bt,
    void* __restrict__ Cv, int M, int N, int K, int relu_limit) {
  __shared__ ushort Asm[128 * 64];
  __shared__ ushort Bsm[128 * 64];

  const int tid  = threadIdx.x;
  const int lane = tid & 63;
  const int w    = tid >> 6;
  const int wr   = w >> 1, wc = w & 1;
  const int brow = blockIdx.y * 128;
  const int bcol = blockIdx.x * 128;

  f32x4 acc[4][4];
  #pragma unroll
  for (int i = 0; i < 4; ++i)
    #pragma unroll
    for (int j = 0; j < 4; ++j) acc[i][j] = (f32x4)0.f;

  const int r8   = lane >> 3;
  const int arow = w * 32 + r8;
  const int acol = ((lane & 7) ^ r8) * 8;
  const ushort* Ag = A  + (size_t)(brow + arow) * K + acol;
  const ushort* Bg = Bt + (size_t)(bcol + arow) * K + acol;

  const int l15 = lane & 15;
  const int khi = (lane >> 4) * 8;

  for (int k0 = 0; k0 < K; k0 += 64) {
    #pragma unroll
    for (int u = 0; u < 4; ++u) {
      gload_lds16(Ag + k0 + (size_t)u * 8 * K, &Asm[(w * 4 + u) * 512]);
      gload_lds16(Bg + k0 + (size_t)u * 8 * K, &Bsm[(w * 4 + u) * 512]);
    }
    __syncthreads();
    #pragma unroll
    for (int kk = 0; kk < 2; ++kk) {
      const int ko = kk * 32 + khi;
      bf16x8 af[4], bfr[4];
      #pragma unroll
      for (int mi = 0; mi < 4; ++mi) {
        const int row = wr * 64 + mi * 16 + l15;
        af[mi] = *(const bf16x8*)&Asm[row * 64 + (ko ^ ((row & 7) << 3))];
      }
      #pragma unroll
      for (int ni = 0; ni < 4; ++ni) {
        const int row = wc * 64 + ni * 16 + l15;
        bfr[ni] = *(const bf16x8*)&Bsm[row * 64 + (ko ^ ((row & 7) << 3))];
      }
      #pragma unroll
      for (int mi = 0; mi < 4; ++mi)
        #pragma unroll
        for (int ni = 0; ni < 4; ++ni)
          acc[mi][ni] = __builtin_amdgcn_mfma_f32_16x16x32_bf16(
              af[mi], bfr[ni], acc[mi][ni], 0, 0, 0);
    }
    __syncthreads();
  }

  #pragma unroll
  for (int mi = 0; mi < 4; ++mi) {
    #pragma unroll
    for (int ni = 0; ni < 4; ++ni) {
      const int r0  = brow + wr * 64 + mi * 16 + (lane >> 4) * 4;
      const int col = bcol + wc * 64 + ni * 16 + l15;
      const bool rl = col < relu_limit;
      #pragma unroll
      for (int i = 0; i < 4; ++i) {
        float v = acc[mi][ni][i];
        if (rl) v = fmaxf(v, 0.f);
        if (OUT_BF16)
          ((ushort*)Cv)[(size_t)(r0 + i) * N + col] = f2bf(v);
        else
          ((float*)Cv)[(size_t)(r0 + i) * N + col] = v;
      }
    }
  }
}

// ---------------------------------------------------------------------------
// Kernel A (MFMA): state[bh,c] = { KVT[e][d] = sum_t V[t][e] K[t][d], ksum[d] }
// ---------------------------------------------------------------------------
__global__ __launch_bounds__(256) void chunk_sums_mfma(
    const ushort* __restrict__ qkvb, float* __restrict__ state) {
  __shared__ ushort Kt[64 * LP];   // Kt[d][t]
  __shared__ ushort Vt[64 * LP];   // Vt[e][t]

  const int bh = blockIdx.x >> 5;
  const int c  = blockIdx.x & (NC - 1);
  const int b  = bh >> 4;
  const int h  = bh & (NHEADS - 1);
  const int tid = threadIdx.x;

  const size_t rs   = 3 * DMODEL;
  const size_t base = ((size_t)(b * SEQ + c * CS)) * rs + (size_t)h * HD;

  const int r  = tid >> 2;          // timestep row 0..63
  const int sg = (tid & 3) * 16;    // col segment
  {
    const ushort* src = qkvb + base + (size_t)r * rs + sg;
    ushort8 k0 = *(const ushort8*)(src + DMODEL);
    ushort8 k1 = *(const ushort8*)(src + DMODEL + 8);
    ushort8 v0 = *(const ushort8*)(src + 2 * DMODEL);
    ushort8 v1 = *(const ushort8*)(src + 2 * DMODEL + 8);
    #pragma unroll
    for (int j = 0; j < 8; ++j) {
      Kt[(sg + j) * LP + r]     = k0[j];
      Kt[(sg + 8 + j) * LP + r] = k1[j];
      Vt[(sg + j) * LP + r]     = v0[j];
      Vt[(sg + 8 + j) * LP + r] = v1[j];
    }
  }
  __syncthreads();

  const int lane = tid & 63;
  const int w    = tid >> 6;
  const int l15  = lane & 15;
  const int khi  = (lane >> 4) * 8;

  bf16x8 va[2];
  #pragma unroll
  for (int kk = 0; kk < 2; ++kk)
    va[kk] = *(const bf16x8*)&Vt[(w * 16 + l15) * LP + kk * 32 + khi];

  f32x4 a[4];
  #pragma unroll
  for (int ct = 0; ct < 4; ++ct) {
    a[ct] = (f32x4)0.f;
    #pragma unroll
    for (int kk = 0; kk < 2; ++kk)
      a[ct] = __builtin_amdgcn_mfma_f32_16x16x32_bf16(
          va[kk], *(const bf16x8*)&Kt[(ct * 16 + l15) * LP + kk * 32 + khi],
          a[ct], 0, 0, 0);
  }

  float* st = state + (size_t)blockIdx.x * STSZ;
  #pragma unroll
  for (int ct = 0; ct < 4; ++ct) {
    #pragma unroll
    for (int i = 0; i < 4; ++i) {
      const int e = w * 16 + (lane >> 4) * 4 + i;
      const int d = ct * 16 + l15;
      st[e * HD + d] = a[ct][i];
    }
  }

  if (tid < HD) {
    float s = 0.f;
    #pragma unroll 8
    for (int t = 0; t < CS; ++t) s += bf2f(Kt[tid * LP + t]);
    st[HD * HD + tid] = s;
  }
}

// ---------------------------------------------------------------------------
// Kernel B: exclusive prefix over chunks, element-parallel (fp32).
// ---------------------------------------------------------------------------
__global__ __launch_bounds__(256) void chunk_prefix(float* __restrict__ state) {
  const int g = blockIdx.x * 256 + threadIdx.x;
  const int total = 2 * NHEADS * STSZ;
  if (g >= total) return;
  const int bh   = g / STSZ;
  const int elem = g - bh * STSZ;
  float* p = state + (size_t)bh * NC * STSZ + elem;

  float vals[NC];
  #pragma unroll
  for (int c = 0; c < NC; ++c) vals[c] = p[(size_t)c * STSZ];
  float run = 0.f;
  #pragma unroll
  for (int c = 0; c < NC; ++c) {
    const float t = vals[c];
    p[(size_t)c * STSZ] = run;
    run += t;
  }
}

// ---------------------------------------------------------------------------
// Kernel C (MFMA): per-(b,h,chunk) output, writes y bf16.
// ---------------------------------------------------------------------------
__global__ __launch_bounds__(256) void chunk_out_mfma(
    const ushort* __restrict__ qkvb, const float* __restrict__ state,
    ushort* __restrict__ y) {
  __shared__ ushort Qs[64 * LP];   // Q[t][d]
  __shared__ ushort Ks[64 * LP];   // K[s][d]
  __shared__ ushort Vt[80 * LP];   // Vaug^T[n][s]: n<64 = V[s][n], n=64: ones
  __shared__ ushort Kv[80 * LP];   // KvAug^T[n][d]: n<64 = KVp[d][n], n=64: ksum
  __shared__ ushort Sm[64 * LP];   // masked S[t][s] bf16

  const int bh = blockIdx.x >> 5;
  const int c  = blockIdx.x & (NC - 1);
  const int b  = bh >> 4;
  const int h  = bh & (NHEADS - 1);
  const int tid = threadIdx.x;

  const size_t rs   = 3 * DMODEL;
  const size_t base = ((size_t)(b * SEQ + c * CS)) * rs + (size_t)h * HD;

  {
    const int r  = tid >> 2;
    const int sg = (tid & 3) * 16;
    const ushort* src = qkvb + base + (size_t)r * rs + sg;
    ushort8 q0 = *(const ushort8*)(src);
    ushort8 q1 = *(const ushort8*)(src + 8);
    ushort8 k0 = *(const ushort8*)(src + DMODEL);
    ushort8 k1 = *(const ushort8*)(src + DMODEL + 8);
    ushort8 v0 = *(const ushort8*)(src + 2 * DMODEL);
    ushort8 v1 = *(const ushort8*)(src + 2 * DMODEL + 8);
    *(ushort8*)&Qs[r * LP + sg]     = q0;
    *(ushort8*)&Qs[r * LP + sg + 8] = q1;
    *(ushort8*)&Ks[r * LP + sg]     = k0;
    *(ushort8*)&Ks[r * LP + sg + 8] = k1;
    #pragma unroll
    for (int j = 0; j < 8; ++j) {
      Vt[(sg + j) * LP + r]     = v0[j];
      Vt[(sg + 8 + j) * LP + r] = v1[j];
    }
  }
  // Vt rows 64..79: row 64 = 1.0, rest 0
  {
    const int idx = tid * 4;                 // 0..1023
    const int row = 64 + (idx >> 6);
    const int col = idx & 63;
    const ushort val = (row == 64) ? (ushort)0x3F80 : (ushort)0;
    ushort4 v4 = {val, val, val, val};
    *(ushort4*)&Vt[row * LP + col] = v4;
  }
  // Kv rows 0..63 from prefixed state (KVT, e-major), row 64 = ksum, 65..79 = 0
  {
    const float* sp = state + ((size_t)bh * NC + c) * STSZ;
    const int off = tid * 16;                // 0..4095
    const int e   = off >> 6;
    const int col = off & 63;
    ushort tmp[16];
    #pragma unroll
    for (int j = 0; j < 4; ++j) {
      float4 f = *(const float4*)(sp + off + j * 4);
      tmp[j * 4 + 0] = f2bf(f.x);
      tmp[j * 4 + 1] = f2bf(f.y);
      tmp[j * 4 + 2] = f2bf(f.z);
      tmp[j * 4 + 3] = f2bf(f.w);
    }
    *(ushort8*)&Kv[e * LP + col]     = *(const ushort8*)&tmp[0];
    *(ushort8*)&Kv[e * LP + col + 8] = *(const ushort8*)&tmp[8];
    if (tid < 16) {
      const int c4 = tid * 4;
      ushort4 v4;
      v4.x = f2bf(sp[HD * HD + c4 + 0]);
      v4.y = f2bf(sp[HD * HD + c4 + 1]);
      v4.z = f2bf(sp[HD * HD + c4 + 2]);
      v4.w = f2bf(sp[HD * HD + c4 + 3]);
      *(ushort4*)&Kv[64 * LP + c4] = v4;
    }
    if (tid < 240) {
      const int idx = tid * 4;               // 0..959
      const int row = 65 + (idx >> 6);
      const int col2 = idx & 63;
      ushort4 z = {0, 0, 0, 0};
      *(ushort4*)&Kv[row * LP + col2] = z;
    }
  }
  __syncthreads();

  const int lane = tid & 63;
  const int w    = tid >> 6;
  const int l15  = lane & 15;
  const int khi  = (lane >> 4) * 8;

  // ---- S = Q K^T for row stripe w*16..w*16+15 ----
  bf16x8 qa[2];
  #pragma unroll
  for (int kk = 0; kk < 2; ++kk)
    qa[kk] = *(const bf16x8*)&Qs[(w * 16 + l15) * LP + kk * 32 + khi];

  {
    f32x4 sac[4];
    #pragma unroll
    for (int ct = 0; ct < 4; ++ct) {
      sac[ct] = (f32x4)0.f;
      #pragma unroll
      for (int kk = 0; kk < 2; ++kk)
        sac[ct] = __builtin_amdgcn_mfma_f32_16x16x32_bf16(
            qa[kk], *(const bf16x8*)&Ks[(ct * 16 + l15) * LP + kk * 32 + khi],
            sac[ct], 0, 0, 0);
    }
    const int t0 = w * 16 + (lane >> 4) * 4;
    #pragma unroll
    for (int ct = 0; ct < 4; ++ct) {
      const int s = ct * 16 + l15;
      #pragma unroll
      for (int i = 0; i < 4; ++i) {
        const int t = t0 + i;
        const float v = (s <= t) ? sac[ct][i] : 0.f;
        Sm[t * LP + s] = f2bf(v);
      }
    }
  }
  __syncthreads();

  // ---- O = Q @ KvAug + Sm @ VtAug  (N = 80) ----
  bf16x8 sa[2];
  #pragma unroll
  for (int kk = 0; kk < 2; ++kk)
    sa[kk] = *(const bf16x8*)&Sm[(w * 16 + l15) * LP + kk * 32 + khi];

  f32x4 o[5];
  #pragma unroll
  for (int ct = 0; ct < 5; ++ct) {
    o[ct] = (f32x4)0.f;
    #pragma unroll
    for (int kk = 0; kk < 2; ++kk)
      o[ct] = __builtin_amdgcn_mfma_f32_16x16x32_bf16(
          qa[kk], *(const bf16x8*)&Kv[(ct * 16 + l15) * LP + kk * 32 + khi],
          o[ct], 0, 0, 0);
    #pragma unroll
    for (int kk = 0; kk < 2; ++kk)
      o[ct] = __builtin_amdgcn_mfma_f32_16x16x32_bf16(
          sa[kk], *(const bf16x8*)&Vt[(ct * 16 + l15) * LP + kk * 32 + khi],
          o[ct], 0, 0, 0);
  }

  // ---- epilogue: den broadcast within 16-lane group, write y ----
  float den[4];
  #pragma unroll
  for (int i = 0; i < 4; ++i)
    den[i] = __shfl(o[4][i], lane & 48) + EPS_LA;

  const int t0 = w * 16 + (lane >> 4) * 4;
  #pragma unroll
  for (int ct = 0; ct < 4; ++ct) {
    const int e = ct * 16 + l15;
    #pragma unroll
    for (int i = 0; i < 4; ++i) {
      const int t = t0 + i;
      y[((size_t)(b * SEQ + c * CS + t)) * DMODEL + (size_t)h * HD + e] =
          f2bf(o[ct][i] / den[i]);
    }
  }
}

// ---------------------------------------------------------------------------
extern "C" void kernel_launch(void* const* d_in, const int* in_sizes, int n_in,
                              void* d_out, int out_size, void* d_ws,
                              size_t ws_size, hipStream_t stream) {
  (void)in_sizes; (void)n_in; (void)out_size; (void)ws_size;
  const float* x    = (const float*)d_in[0];
  const float* wqkv = (const float*)d_in[1];
  const float* wo   = (const float*)d_in[2];
  float* out = (float*)d_out;

  const int M  = 2 * SEQ;     // 4096
  const int K  = DMODEL;      // 1024
  const int N1 = 3 * DMODEL;  // 3072
  const int N2 = DMODEL;      // 1024

  // workspace layout (~67.6 MiB)
  float*  state = (float*)d_ws;                           // 16.25 MiB
  ushort* qkvb  = (ushort*)(state + (size_t)2 * NHEADS * NC * STSZ); // 24 MiB
  ushort* xb    = qkvb + (size_t)M * N1;                  // 8 MiB
  ushort* yb    = xb + (size_t)M * K;                     // 8 MiB
  ushort* wqkvT = yb + (size_t)M * K;                     // 6 MiB
  ushort* woT   = wqkvT + (size_t)K * N1;                 // 2 MiB

  dim3 blk(256);

  conv_bf16<<<dim3((M * K) / 1024), blk, 0, stream>>>(x, xb);
  transpose_to_bf16<<<dim3(N1 / 64, K / 64), blk, 0, stream>>>(wqkv, wqkvT, K, N1);
  transpose_to_bf16<<<dim3(N2 / 64, K / 64), blk, 0, stream>>>(wo, woT, K, N2);

  // GEMM1: 256^2 phased kernel, grid 16x12 = 192 blocks (192 % 8 == 0)
  gemm_8ph<true><<<dim3((M / 256) * (N1 / 256)), dim3(512), 0, stream>>>(
      xb, wqkvT, qkvb, M, N1, K, 2 * DMODEL, N1 / 256);

  chunk_sums_mfma<<<dim3(2 * NHEADS * NC), blk, 0, stream>>>(qkvb, state);

  const int total = 2 * NHEADS * STSZ;
  chunk_prefix<<<dim3((total + 255) / 256), blk, 0, stream>>>(state);

  chunk_out_mfma<<<dim3(2 * NHEADS * NC), blk, 0, stream>>>(qkvb, state, yb);

  // GEMM2: 128^2 swizzled (256 blocks = exactly one full CU round)
  gemm_swz<false><<<dim3(N2 / 128, M / 128), blk, 0, stream>>>(
      yb, woT, out, M, N2, K, 0);
}

// Round 9
// 89.766 us; speedup vs baseline: 1.1135x; 1.1135x over previous
//
#include <hip/hip_runtime.h>
#include <hip/hip_bf16.h>

#define SEQ    2048
#define DMODEL 1024
#define NHEADS 16
#define HD     64
#define CS     64
#define NC     (SEQ / CS)
#define STSZ   (HD * HD + HD)   // 4160 bf16: KVT[64][64] + ksum[64]
#define EPS_LA 1e-5f
#define LP     72               // padded LDS row stride (bf16 elems)

typedef __attribute__((ext_vector_type(8))) short  bf16x8;
typedef __attribute__((ext_vector_type(8))) unsigned short ushort8;
typedef __attribute__((ext_vector_type(4))) float  f32x4;

__device__ __forceinline__ void gload_lds16(const void* g, void* l) {
  __builtin_amdgcn_global_load_lds(
      (const __attribute__((address_space(1))) void*)g,
      (__attribute__((address_space(3))) void*)l, 16, 0, 0);
}

__device__ __forceinline__ ushort f2bf(float x) {
  __hip_bfloat16 h = __float2bfloat16(x);
  return __builtin_bit_cast(ushort, h);
}
__device__ __forceinline__ float bf2f(ushort u) {
  unsigned int v = ((unsigned int)u) << 16;
  return __builtin_bit_cast(float, v);
}

// ---------------------------------------------------------------------------
// Fused prep: blocks [0,4096) convert x f32->bf16; [4096,4864) transpose wqkv
// -> wqkvT (3072x1024); [4864,5120) transpose wo -> woT (1024x1024).
// All branches are block-uniform.
// ---------------------------------------------------------------------------
__device__ __forceinline__ void transpose_tile(
    const float* __restrict__ src, ushort* __restrict__ dst,
    int R, int Ncols, int r0, int c0, float (*t)[65], int tid) {
  const int lr = tid >> 2;
  const int lc = (tid & 3) * 16;
  const float* sp = src + (size_t)(r0 + lr) * Ncols + c0 + lc;
  #pragma unroll
  for (int j = 0; j < 4; ++j) {
    float4 v = *(const float4*)(sp + j * 4);
    t[lr][lc + j * 4 + 0] = v.x;
    t[lr][lc + j * 4 + 1] = v.y;
    t[lr][lc + j * 4 + 2] = v.z;
    t[lr][lc + j * 4 + 3] = v.w;
  }
  __syncthreads();
  ushort out[16];
  #pragma unroll
  for (int j = 0; j < 16; ++j)
    out[j] = f2bf(t[lc + j][lr]);
  ushort* dp = dst + (size_t)(c0 + lr) * R + r0 + lc;
  *(uint4*)dp = *(const uint4*)&out[0];
  *(uint4*)(dp + 8) = *(const uint4*)&out[8];
}

__global__ __launch_bounds__(256) void prep(
    const float* __restrict__ x, const float* __restrict__ wqkv,
    const float* __restrict__ wo, ushort* __restrict__ xb,
    ushort* __restrict__ wqkvT, ushort* __restrict__ woT) {
  __shared__ float t[64][65];
  const int bid = blockIdx.x;
  const int tid = threadIdx.x;
  if (bid < 4096) {
    const int i = bid * 256 + tid;
    float4 v = *(const float4*)(x + (size_t)i * 4);
    ushort4 o;
    o.x = f2bf(v.x); o.y = f2bf(v.y); o.z = f2bf(v.z); o.w = f2bf(v.w);
    *(ushort4*)(xb + (size_t)i * 4) = o;
  } else if (bid < 4096 + 768) {
    const int b2 = bid - 4096;             // wqkv: 1024 x 3072 -> 48 x 16 tiles
    const int bx = b2 % 48, by = b2 / 48;
    transpose_tile(wqkv, wqkvT, DMODEL, 3 * DMODEL, by * 64, bx * 64, t, tid);
  } else {
    const int b3 = bid - 4096 - 768;       // wo: 1024 x 1024 -> 16 x 16 tiles
    const int bx = b3 % 16, by = b3 / 16;
    transpose_tile(wo, woT, DMODEL, DMODEL, by * 64, bx * 64, t, tid);
  }
}

// ---------------------------------------------------------------------------
// 128x128 2-phase swizzled GEMM (round-7, proven).
// ---------------------------------------------------------------------------
template <bool OUT_BF16>
__global__ __launch_bounds__(256) void gemm_swz(
    const ushort* __restrict__ A, const ushort* __restrict__ Bt,
    void* __restrict__ Cv, int M, int N, int K, int relu_limit) {
  __shared__ ushort Asm[128 * 64];
  __shared__ ushort Bsm[128 * 64];

  const int tid  = threadIdx.x;
  const int lane = tid & 63;
  const int w    = tid >> 6;
  const int wr   = w >> 1, wc = w & 1;
  const int brow = blockIdx.y * 128;
  const int bcol = blockIdx.x * 128;

  f32x4 acc[4][4];
  #pragma unroll
  for (int i = 0; i < 4; ++i)
    #pragma unroll
    for (int j = 0; j < 4; ++j) acc[i][j] = (f32x4)0.f;

  const int r8   = lane >> 3;
  const int arow = w * 32 + r8;
  const int acol = ((lane & 7) ^ r8) * 8;   // pre-swizzled global source col
  const ushort* Ag = A  + (size_t)(brow + arow) * K + acol;
  const ushort* Bg = Bt + (size_t)(bcol + arow) * K + acol;

  const int l15 = lane & 15;
  const int khi = (lane >> 4) * 8;

  for (int k0 = 0; k0 < K; k0 += 64) {
    #pragma unroll
    for (int u = 0; u < 4; ++u) {
      gload_lds16(Ag + k0 + (size_t)u * 8 * K, &Asm[(w * 4 + u) * 512]);
      gload_lds16(Bg + k0 + (size_t)u * 8 * K, &Bsm[(w * 4 + u) * 512]);
    }
    __syncthreads();
    #pragma unroll
    for (int kk = 0; kk < 2; ++kk) {
      const int ko = kk * 32 + khi;
      bf16x8 af[4], bfr[4];
      #pragma unroll
      for (int mi = 0; mi < 4; ++mi) {
        const int row = wr * 64 + mi * 16 + l15;
        af[mi] = *(const bf16x8*)&Asm[row * 64 + (ko ^ ((row & 7) << 3))];
      }
      #pragma unroll
      for (int ni = 0; ni < 4; ++ni) {
        const int row = wc * 64 + ni * 16 + l15;
        bfr[ni] = *(const bf16x8*)&Bsm[row * 64 + (ko ^ ((row & 7) << 3))];
      }
      #pragma unroll
      for (int mi = 0; mi < 4; ++mi)
        #pragma unroll
        for (int ni = 0; ni < 4; ++ni)
          acc[mi][ni] = __builtin_amdgcn_mfma_f32_16x16x32_bf16(
              af[mi], bfr[ni], acc[mi][ni], 0, 0, 0);
    }
    __syncthreads();
  }

  #pragma unroll
  for (int mi = 0; mi < 4; ++mi) {
    #pragma unroll
    for (int ni = 0; ni < 4; ++ni) {
      const int r0  = brow + wr * 64 + mi * 16 + (lane >> 4) * 4;
      const int col = bcol + wc * 64 + ni * 16 + l15;
      const bool rl = col < relu_limit;
      #pragma unroll
      for (int i = 0; i < 4; ++i) {
        float v = acc[mi][ni][i];
        if (rl) v = fmaxf(v, 0.f);
        if (OUT_BF16)
          ((ushort*)Cv)[(size_t)(r0 + i) * N + col] = f2bf(v);
        else
          ((float*)Cv)[(size_t)(r0 + i) * N + col] = v;
      }
    }
  }
}

// ---------------------------------------------------------------------------
// Kernel A (MFMA): state[bh,c] = { KVT[e][d] = sum_t V[t][e] K[t][d], ksum[d] }
// state now bf16.
// ---------------------------------------------------------------------------
__global__ __launch_bounds__(256) void chunk_sums_mfma(
    const ushort* __restrict__ qkvb, ushort* __restrict__ state) {
  __shared__ ushort Kt[64 * LP];   // Kt[d][t]
  __shared__ ushort Vt[64 * LP];   // Vt[e][t]

  const int bh = blockIdx.x >> 5;
  const int c  = blockIdx.x & (NC - 1);
  const int b  = bh >> 4;
  const int h  = bh & (NHEADS - 1);
  const int tid = threadIdx.x;

  const size_t rs   = 3 * DMODEL;
  const size_t base = ((size_t)(b * SEQ + c * CS)) * rs + (size_t)h * HD;

  const int r  = tid >> 2;          // timestep row 0..63
  const int sg = (tid & 3) * 16;    // col segment
  {
    const ushort* src = qkvb + base + (size_t)r * rs + sg;
    ushort8 k0 = *(const ushort8*)(src + DMODEL);
    ushort8 k1 = *(const ushort8*)(src + DMODEL + 8);
    ushort8 v0 = *(const ushort8*)(src + 2 * DMODEL);
    ushort8 v1 = *(const ushort8*)(src + 2 * DMODEL + 8);
    #pragma unroll
    for (int j = 0; j < 8; ++j) {
      Kt[(sg + j) * LP + r]     = k0[j];
      Kt[(sg + 8 + j) * LP + r] = k1[j];
      Vt[(sg + j) * LP + r]     = v0[j];
      Vt[(sg + 8 + j) * LP + r] = v1[j];
    }
  }
  __syncthreads();

  const int lane = tid & 63;
  const int w    = tid >> 6;
  const int l15  = lane & 15;
  const int khi  = (lane >> 4) * 8;

  bf16x8 va[2];
  #pragma unroll
  for (int kk = 0; kk < 2; ++kk)
    va[kk] = *(const bf16x8*)&Vt[(w * 16 + l15) * LP + kk * 32 + khi];

  f32x4 a[4];
  #pragma unroll
  for (int ct = 0; ct < 4; ++ct) {
    a[ct] = (f32x4)0.f;
    #pragma unroll
    for (int kk = 0; kk < 2; ++kk)
      a[ct] = __builtin_amdgcn_mfma_f32_16x16x32_bf16(
          va[kk], *(const bf16x8*)&Kt[(ct * 16 + l15) * LP + kk * 32 + khi],
          a[ct], 0, 0, 0);
  }

  ushort* st = state + (size_t)blockIdx.x * STSZ;
  #pragma unroll
  for (int ct = 0; ct < 4; ++ct) {
    #pragma unroll
    for (int i = 0; i < 4; ++i) {
      const int e = w * 16 + (lane >> 4) * 4 + i;
      const int d = ct * 16 + l15;
      st[e * HD + d] = f2bf(a[ct][i]);
    }
  }

  if (tid < HD) {
    float s = 0.f;
    #pragma unroll 8
    for (int t = 0; t < CS; ++t) s += bf2f(Kt[tid * LP + t]);
    st[HD * HD + tid] = f2bf(s);
  }
}

// ---------------------------------------------------------------------------
// Kernel B: exclusive prefix over chunks, element-parallel. bf16 in/out,
// f32 running accumulator in registers.
// ---------------------------------------------------------------------------
__global__ __launch_bounds__(256) void chunk_prefix(ushort* __restrict__ state) {
  const int g = blockIdx.x * 256 + threadIdx.x;
  const int total = 2 * NHEADS * STSZ;
  if (g >= total) return;
  const int bh   = g / STSZ;
  const int elem = g - bh * STSZ;
  ushort* p = state + (size_t)bh * NC * STSZ + elem;

  float run = 0.f;
  #pragma unroll
  for (int c = 0; c < NC; ++c) {
    const float t = bf2f(p[(size_t)c * STSZ]);
    p[(size_t)c * STSZ] = f2bf(run);
    run += t;
  }
}

// ---------------------------------------------------------------------------
// Kernel C (MFMA): per-(b,h,chunk) output, writes y bf16. state is bf16.
// ---------------------------------------------------------------------------
__global__ __launch_bounds__(256) void chunk_out_mfma(
    const ushort* __restrict__ qkvb, const ushort* __restrict__ state,
    ushort* __restrict__ y) {
  __shared__ ushort Qs[64 * LP];   // Q[t][d]
  __shared__ ushort Ks[64 * LP];   // K[s][d]
  __shared__ ushort Vt[80 * LP];   // Vaug^T[n][s]: n<64 = V[s][n], n=64: ones
  __shared__ ushort Kv[80 * LP];   // KvAug^T[n][d]: n<64 = KVp[d][n], n=64: ksum
  __shared__ ushort Sm[64 * LP];   // masked S[t][s] bf16

  const int bh = blockIdx.x >> 5;
  const int c  = blockIdx.x & (NC - 1);
  const int b  = bh >> 4;
  const int h  = bh & (NHEADS - 1);
  const int tid = threadIdx.x;

  const size_t rs   = 3 * DMODEL;
  const size_t base = ((size_t)(b * SEQ + c * CS)) * rs + (size_t)h * HD;

  {
    const int r  = tid >> 2;
    const int sg = (tid & 3) * 16;
    const ushort* src = qkvb + base + (size_t)r * rs + sg;
    ushort8 q0 = *(const ushort8*)(src);
    ushort8 q1 = *(const ushort8*)(src + 8);
    ushort8 k0 = *(const ushort8*)(src + DMODEL);
    ushort8 k1 = *(const ushort8*)(src + DMODEL + 8);
    ushort8 v0 = *(const ushort8*)(src + 2 * DMODEL);
    ushort8 v1 = *(const ushort8*)(src + 2 * DMODEL + 8);
    *(ushort8*)&Qs[r * LP + sg]     = q0;
    *(ushort8*)&Qs[r * LP + sg + 8] = q1;
    *(ushort8*)&Ks[r * LP + sg]     = k0;
    *(ushort8*)&Ks[r * LP + sg + 8] = k1;
    #pragma unroll
    for (int j = 0; j < 8; ++j) {
      Vt[(sg + j) * LP + r]     = v0[j];
      Vt[(sg + 8 + j) * LP + r] = v1[j];
    }
  }
  // Vt rows 64..79: row 64 = 1.0, rest 0
  {
    const int idx = tid * 4;                 // 0..1023
    const int row = 64 + (idx >> 6);
    const int col = idx & 63;
    const ushort val = (row == 64) ? (ushort)0x3F80 : (ushort)0;
    ushort4 v4 = {val, val, val, val};
    *(ushort4*)&Vt[row * LP + col] = v4;
  }
  // Kv rows 0..63 direct bf16 copy; row 64 = ksum; rows 65..79 = 0
  {
    const ushort* sp = state + ((size_t)bh * NC + c) * STSZ;
    const int off = tid * 16;                // 0..4095
    const int e   = off >> 6;
    const int col = off & 63;
    *(ushort8*)&Kv[e * LP + col]     = *(const ushort8*)(sp + off);
    *(ushort8*)&Kv[e * LP + col + 8] = *(const ushort8*)(sp + off + 8);
    if (tid < 16) {
      const int c4 = tid * 4;
      *(ushort4*)&Kv[64 * LP + c4] = *(const ushort4*)(sp + HD * HD + c4);
    }
    if (tid < 240) {
      const int idx = tid * 4;               // 0..959
      const int row = 65 + (idx >> 6);
      const int col2 = idx & 63;
      ushort4 z = {0, 0, 0, 0};
      *(ushort4*)&Kv[row * LP + col2] = z;
    }
  }
  __syncthreads();

  const int lane = tid & 63;
  const int w    = tid >> 6;
  const int l15  = lane & 15;
  const int khi  = (lane >> 4) * 8;

  // ---- S = Q K^T for row stripe w*16..w*16+15 ----
  bf16x8 qa[2];
  #pragma unroll
  for (int kk = 0; kk < 2; ++kk)
    qa[kk] = *(const bf16x8*)&Qs[(w * 16 + l15) * LP + kk * 32 + khi];

  {
    f32x4 sac[4];
    #pragma unroll
    for (int ct = 0; ct < 4; ++ct) {
      sac[ct] = (f32x4)0.f;
      #pragma unroll
      for (int kk = 0; kk < 2; ++kk)
        sac[ct] = __builtin_amdgcn_mfma_f32_16x16x32_bf16(
            qa[kk], *(const bf16x8*)&Ks[(ct * 16 + l15) * LP + kk * 32 + khi],
            sac[ct], 0, 0, 0);
    }
    const int t0 = w * 16 + (lane >> 4) * 4;
    #pragma unroll
    for (int ct = 0; ct < 4; ++ct) {
      const int s = ct * 16 + l15;
      #pragma unroll
      for (int i = 0; i < 4; ++i) {
        const int t = t0 + i;
        const float v = (s <= t) ? sac[ct][i] : 0.f;
        Sm[t * LP + s] = f2bf(v);
      }
    }
  }
  __syncthreads();

  // ---- O = Q @ KvAug + Sm @ VtAug  (N = 80) ----
  bf16x8 sa[2];
  #pragma unroll
  for (int kk = 0; kk < 2; ++kk)
    sa[kk] = *(const bf16x8*)&Sm[(w * 16 + l15) * LP + kk * 32 + khi];

  f32x4 o[5];
  #pragma unroll
  for (int ct = 0; ct < 5; ++ct) {
    o[ct] = (f32x4)0.f;
    #pragma unroll
    for (int kk = 0; kk < 2; ++kk)
      o[ct] = __builtin_amdgcn_mfma_f32_16x16x32_bf16(
          qa[kk], *(const bf16x8*)&Kv[(ct * 16 + l15) * LP + kk * 32 + khi],
          o[ct], 0, 0, 0);
    #pragma unroll
    for (int kk = 0; kk < 2; ++kk)
      o[ct] = __builtin_amdgcn_mfma_f32_16x16x32_bf16(
          sa[kk], *(const bf16x8*)&Vt[(ct * 16 + l15) * LP + kk * 32 + khi],
          o[ct], 0, 0, 0);
  }

  // ---- epilogue: den broadcast within 16-lane group, write y ----
  float den[4];
  #pragma unroll
  for (int i = 0; i < 4; ++i)
    den[i] = __shfl(o[4][i], lane & 48) + EPS_LA;

  const int t0 = w * 16 + (lane >> 4) * 4;
  #pragma unroll
  for (int ct = 0; ct < 4; ++ct) {
    const int e = ct * 16 + l15;
    #pragma unroll
    for (int i = 0; i < 4; ++i) {
      const int t = t0 + i;
      y[((size_t)(b * SEQ + c * CS + t)) * DMODEL + (size_t)h * HD + e] =
          f2bf(o[ct][i] / den[i]);
    }
  }
}

// ---------------------------------------------------------------------------
extern "C" void kernel_launch(void* const* d_in, const int* in_sizes, int n_in,
                              void* d_out, int out_size, void* d_ws,
                              size_t ws_size, hipStream_t stream) {
  (void)in_sizes; (void)n_in; (void)out_size; (void)ws_size;
  const float* x    = (const float*)d_in[0];
  const float* wqkv = (const float*)d_in[1];
  const float* wo   = (const float*)d_in[2];
  float* out = (float*)d_out;

  const int M  = 2 * SEQ;     // 4096
  const int K  = DMODEL;      // 1024
  const int N1 = 3 * DMODEL;  // 3072
  const int N2 = DMODEL;      // 1024

  // workspace layout (~56 MiB)
  ushort* stateb = (ushort*)d_ws;                          // 8.125 MiB
  ushort* qkvb   = stateb + (size_t)2 * NHEADS * NC * STSZ; // 24 MiB
  ushort* xb     = qkvb + (size_t)M * N1;                  // 8 MiB
  ushort* yb     = xb + (size_t)M * K;                     // 8 MiB
  ushort* wqkvT  = yb + (size_t)M * K;                     // 6 MiB
  ushort* woT    = wqkvT + (size_t)K * N1;                 // 2 MiB

  dim3 blk(256);

  // fused prep: conv (4096 blocks) + wqkv transpose (768) + wo transpose (256)
  prep<<<dim3(4096 + 768 + 256), blk, 0, stream>>>(x, wqkv, wo, xb, wqkvT, woT);

  gemm_swz<true><<<dim3(N1 / 128, M / 128), blk, 0, stream>>>(
      xb, wqkvT, qkvb, M, N1, K, 2 * DMODEL);

  chunk_sums_mfma<<<dim3(2 * NHEADS * NC), blk, 0, stream>>>(qkvb, stateb);

  const int total = 2 * NHEADS * STSZ;
  chunk_prefix<<<dim3((total + 255) / 256), blk, 0, stream>>>(stateb);

  chunk_out_mfma<<<dim3(2 * NHEADS * NC), blk, 0, stream>>>(qkvb, stateb, yb);

  gemm_swz<false><<<dim3(N2 / 128, M / 128), blk, 0, stream>>>(
      yb, woT, out, M, N2, K, 0);
}

// Round 10
// 88.995 us; speedup vs baseline: 1.1231x; 1.0087x over previous
//
#include <hip/hip_runtime.h>
#include <hip/hip_bf16.h>

#define SEQ    2048
#define DMODEL 1024
#define NHEADS 16
#define HD     64
#define CS     64
#define NC     (SEQ / CS)
#define STSZ   (HD * HD + HD)   // 4160 bf16: KVT[64][64] + ksum[64]
#define EPS_LA 1e-5f
#define LP     72               // padded LDS row stride (bf16 elems)

typedef __attribute__((ext_vector_type(8))) short  bf16x8;
typedef __attribute__((ext_vector_type(8))) unsigned short ushort8;
typedef __attribute__((ext_vector_type(4))) float  f32x4;

__device__ __forceinline__ void gload_lds16(const void* g, void* l) {
  __builtin_amdgcn_global_load_lds(
      (const __attribute__((address_space(1))) void*)g,
      (__attribute__((address_space(3))) void*)l, 16, 0, 0);
}

__device__ __forceinline__ ushort f2bf(float x) {
  __hip_bfloat16 h = __float2bfloat16(x);
  return __builtin_bit_cast(ushort, h);
}
__device__ __forceinline__ float bf2f(ushort u) {
  unsigned int v = ((unsigned int)u) << 16;
  return __builtin_bit_cast(float, v);
}

// ---------------------------------------------------------------------------
// Fused prep: blocks [0,4096) convert x f32->bf16; [4096,4864) transpose wqkv
// -> wqkvT (3072x1024); [4864,5120) transpose wo -> woT (1024x1024).
// ---------------------------------------------------------------------------
__device__ __forceinline__ void transpose_tile(
    const float* __restrict__ src, ushort* __restrict__ dst,
    int R, int Ncols, int r0, int c0, float (*t)[65], int tid) {
  const int lr = tid >> 2;
  const int lc = (tid & 3) * 16;
  const float* sp = src + (size_t)(r0 + lr) * Ncols + c0 + lc;
  #pragma unroll
  for (int j = 0; j < 4; ++j) {
    float4 v = *(const float4*)(sp + j * 4);
    t[lr][lc + j * 4 + 0] = v.x;
    t[lr][lc + j * 4 + 1] = v.y;
    t[lr][lc + j * 4 + 2] = v.z;
    t[lr][lc + j * 4 + 3] = v.w;
  }
  __syncthreads();
  ushort out[16];
  #pragma unroll
  for (int j = 0; j < 16; ++j)
    out[j] = f2bf(t[lc + j][lr]);
  ushort* dp = dst + (size_t)(c0 + lr) * R + r0 + lc;
  *(uint4*)dp = *(const uint4*)&out[0];
  *(uint4*)(dp + 8) = *(const uint4*)&out[8];
}

__global__ __launch_bounds__(256) void prep(
    const float* __restrict__ x, const float* __restrict__ wqkv,
    const float* __restrict__ wo, ushort* __restrict__ xb,
    ushort* __restrict__ wqkvT, ushort* __restrict__ woT) {
  __shared__ float t[64][65];
  const int bid = blockIdx.x;
  const int tid = threadIdx.x;
  if (bid < 4096) {
    const int i = bid * 256 + tid;
    float4 v = *(const float4*)(x + (size_t)i * 4);
    ushort4 o;
    o.x = f2bf(v.x); o.y = f2bf(v.y); o.z = f2bf(v.z); o.w = f2bf(v.w);
    *(ushort4*)(xb + (size_t)i * 4) = o;
  } else if (bid < 4096 + 768) {
    const int b2 = bid - 4096;             // wqkv: 1024 x 3072 -> 48 x 16 tiles
    const int bx = b2 % 48, by = b2 / 48;
    transpose_tile(wqkv, wqkvT, DMODEL, 3 * DMODEL, by * 64, bx * 64, t, tid);
  } else {
    const int b3 = bid - 4096 - 768;       // wo: 1024 x 1024 -> 16 x 16 tiles
    const int bx = b3 % 16, by = b3 / 16;
    transpose_tile(wo, woT, DMODEL, DMODEL, by * 64, bx * 64, t, tid);
  }
}

// ---------------------------------------------------------------------------
// Phased 128x128 bf16 MFMA GEMM: dbuf LDS (64 KiB), 2 phases/K-tile, raw
// s_barrier + setprio around MFMA, stage-quarters of next tile issued inside
// phases (fly under MFMA cover), ONE __syncthreads (vmcnt drain) per K-tile.
// XOR swizzle identical to proven round-7 scheme. XCD-aware 1D grid remap.
// ---------------------------------------------------------------------------
template <bool OUT_BF16>
__global__ __launch_bounds__(256) void gemm_ph(
    const ushort* __restrict__ A, const ushort* __restrict__ Bt,
    void* __restrict__ Cv, int M, int N, int K, int relu_limit, int nbx) {
  __shared__ ushort Asm[2][128 * 64];
  __shared__ ushort Bsm[2][128 * 64];

  // XCD-aware bijective remap (gridDim.x % 8 == 0)
  int wg = blockIdx.x;
  const int cpx = gridDim.x >> 3;
  wg = (wg & 7) * cpx + (wg >> 3);
  const int bx = wg % nbx;
  const int by = wg / nbx;
  const int brow = by * 128;
  const int bcol = bx * 128;

  const int tid  = threadIdx.x;
  const int lane = tid & 63;
  const int w    = tid >> 6;
  const int wr   = w >> 1, wc = w & 1;

  f32x4 acc[4][4];
  #pragma unroll
  for (int i = 0; i < 4; ++i)
    #pragma unroll
    for (int j = 0; j < 4; ++j) acc[i][j] = (f32x4)0.f;

  const int r8   = lane >> 3;
  const int arow = w * 32 + r8;                 // + u*8
  const int acol = ((lane & 7) ^ r8) * 8;       // pre-swizzled global source col
  const ushort* Ag = A  + (size_t)(brow + arow) * K + acol;
  const ushort* Bg = Bt + (size_t)(bcol + arow) * K + acol;

  const int l15 = lane & 15;
  const int khi = (lane >> 4) * 8;

  // prologue: stage K-tile 0 into buf 0
  #pragma unroll
  for (int u = 0; u < 4; ++u) {
    gload_lds16(Ag + (size_t)u * 8 * K, &Asm[0][(w * 4 + u) * 512]);
    gload_lds16(Bg + (size_t)u * 8 * K, &Bsm[0][(w * 4 + u) * 512]);
  }
  __syncthreads();

  const int NT = K >> 6;
  int cur = 0;
  for (int kt = 0; kt < NT; ++kt) {
    const ushort* An = Ag + (size_t)(kt + 1) * 64;
    const ushort* Bn = Bg + (size_t)(kt + 1) * 64;
    const bool pf = (kt + 1 < NT);
    #pragma unroll
    for (int ph = 0; ph < 2; ++ph) {
      const int ko = ph * 32 + khi;
      // ---- ds_read this phase's fragments (compiler inserts lgkm waits) ----
      bf16x8 af[4], bfr[4];
      #pragma unroll
      for (int mi = 0; mi < 4; ++mi) {
        const int row = wr * 64 + mi * 16 + l15;
        af[mi] = *(const bf16x8*)&Asm[cur][row * 64 + (ko ^ ((row & 7) << 3))];
      }
      #pragma unroll
      for (int ni = 0; ni < 4; ++ni) {
        const int row = wc * 64 + ni * 16 + l15;
        bfr[ni] = *(const bf16x8*)&Bsm[cur][row * 64 + (ko ^ ((row & 7) << 3))];
      }
      // ---- issue 2A+2B stage-quarters of NEXT tile into the other buffer ----
      if (pf) {
        #pragma unroll
        for (int u = ph * 2; u < ph * 2 + 2; ++u) {
          gload_lds16(An + (size_t)u * 8 * K, &Asm[cur ^ 1][(w * 4 + u) * 512]);
          gload_lds16(Bn + (size_t)u * 8 * K, &Bsm[cur ^ 1][(w * 4 + u) * 512]);
        }
      }
      __builtin_amdgcn_s_barrier();   // raw: aligns waves, no counter drain
      __builtin_amdgcn_s_setprio(1);
      #pragma unroll
      for (int mi = 0; mi < 4; ++mi)
        #pragma unroll
        for (int ni = 0; ni < 4; ++ni)
          acc[mi][ni] = __builtin_amdgcn_mfma_f32_16x16x32_bf16(
              af[mi], bfr[ni], acc[mi][ni], 0, 0, 0);
      __builtin_amdgcn_s_setprio(0);
    }
    __syncthreads();   // full drain once per K-tile: next tile staged
    cur ^= 1;
  }

  #pragma unroll
  for (int mi = 0; mi < 4; ++mi) {
    #pragma unroll
    for (int ni = 0; ni < 4; ++ni) {
      const int r0  = brow + wr * 64 + mi * 16 + (lane >> 4) * 4;
      const int col = bcol + wc * 64 + ni * 16 + l15;
      const bool rl = col < relu_limit;
      #pragma unroll
      for (int i = 0; i < 4; ++i) {
        float v = acc[mi][ni][i];
        if (rl) v = fmaxf(v, 0.f);
        if (OUT_BF16)
          ((ushort*)Cv)[(size_t)(r0 + i) * N + col] = f2bf(v);
        else
          ((float*)Cv)[(size_t)(r0 + i) * N + col] = v;
      }
    }
  }
}

// ---------------------------------------------------------------------------
// Kernel A (MFMA): state[bh,c] = { KVT[e][d] = sum_t V[t][e] K[t][d], ksum[d] }
// state bf16.
// ---------------------------------------------------------------------------
__global__ __launch_bounds__(256) void chunk_sums_mfma(
    const ushort* __restrict__ qkvb, ushort* __restrict__ state) {
  __shared__ ushort Kt[64 * LP];   // Kt[d][t]
  __shared__ ushort Vt[64 * LP];   // Vt[e][t]

  const int bh = blockIdx.x >> 5;
  const int c  = blockIdx.x & (NC - 1);
  const int b  = bh >> 4;
  const int h  = bh & (NHEADS - 1);
  const int tid = threadIdx.x;

  const size_t rs   = 3 * DMODEL;
  const size_t base = ((size_t)(b * SEQ + c * CS)) * rs + (size_t)h * HD;

  const int r  = tid >> 2;          // timestep row 0..63
  const int sg = (tid & 3) * 16;    // col segment
  {
    const ushort* src = qkvb + base + (size_t)r * rs + sg;
    ushort8 k0 = *(const ushort8*)(src + DMODEL);
    ushort8 k1 = *(const ushort8*)(src + DMODEL + 8);
    ushort8 v0 = *(const ushort8*)(src + 2 * DMODEL);
    ushort8 v1 = *(const ushort8*)(src + 2 * DMODEL + 8);
    #pragma unroll
    for (int j = 0; j < 8; ++j) {
      Kt[(sg + j) * LP + r]     = k0[j];
      Kt[(sg + 8 + j) * LP + r] = k1[j];
      Vt[(sg + j) * LP + r]     = v0[j];
      Vt[(sg + 8 + j) * LP + r] = v1[j];
    }
  }
  __syncthreads();

  const int lane = tid & 63;
  const int w    = tid >> 6;
  const int l15  = lane & 15;
  const int khi  = (lane >> 4) * 8;

  bf16x8 va[2];
  #pragma unroll
  for (int kk = 0; kk < 2; ++kk)
    va[kk] = *(const bf16x8*)&Vt[(w * 16 + l15) * LP + kk * 32 + khi];

  f32x4 a[4];
  #pragma unroll
  for (int ct = 0; ct < 4; ++ct) {
    a[ct] = (f32x4)0.f;
    #pragma unroll
    for (int kk = 0; kk < 2; ++kk)
      a[ct] = __builtin_amdgcn_mfma_f32_16x16x32_bf16(
          va[kk], *(const bf16x8*)&Kt[(ct * 16 + l15) * LP + kk * 32 + khi],
          a[ct], 0, 0, 0);
  }

  ushort* st = state + (size_t)blockIdx.x * STSZ;
  #pragma unroll
  for (int ct = 0; ct < 4; ++ct) {
    #pragma unroll
    for (int i = 0; i < 4; ++i) {
      const int e = w * 16 + (lane >> 4) * 4 + i;
      const int d = ct * 16 + l15;
      st[e * HD + d] = f2bf(a[ct][i]);
    }
  }

  if (tid < HD) {
    float s = 0.f;
    #pragma unroll 8
    for (int t = 0; t < CS; ++t) s += bf2f(Kt[tid * LP + t]);
    st[HD * HD + tid] = f2bf(s);
  }
}

// ---------------------------------------------------------------------------
// Kernel B: exclusive prefix over chunks, element-parallel. bf16 in/out,
// f32 running accumulator.
// ---------------------------------------------------------------------------
__global__ __launch_bounds__(256) void chunk_prefix(ushort* __restrict__ state) {
  const int g = blockIdx.x * 256 + threadIdx.x;
  const int total = 2 * NHEADS * STSZ;
  if (g >= total) return;
  const int bh   = g / STSZ;
  const int elem = g - bh * STSZ;
  ushort* p = state + (size_t)bh * NC * STSZ + elem;

  float run = 0.f;
  #pragma unroll
  for (int c = 0; c < NC; ++c) {
    const float t = bf2f(p[(size_t)c * STSZ]);
    p[(size_t)c * STSZ] = f2bf(run);
    run += t;
  }
}

// ---------------------------------------------------------------------------
// Kernel C (MFMA): per-(b,h,chunk) output, writes y bf16. state bf16.
// ---------------------------------------------------------------------------
__global__ __launch_bounds__(256) void chunk_out_mfma(
    const ushort* __restrict__ qkvb, const ushort* __restrict__ state,
    ushort* __restrict__ y) {
  __shared__ ushort Qs[64 * LP];   // Q[t][d]
  __shared__ ushort Ks[64 * LP];   // K[s][d]
  __shared__ ushort Vt[80 * LP];   // Vaug^T[n][s]: n<64 = V[s][n], n=64: ones
  __shared__ ushort Kv[80 * LP];   // KvAug^T[n][d]: n<64 = KVp[d][n], n=64: ksum
  __shared__ ushort Sm[64 * LP];   // masked S[t][s] bf16

  const int bh = blockIdx.x >> 5;
  const int c  = blockIdx.x & (NC - 1);
  const int b  = bh >> 4;
  const int h  = bh & (NHEADS - 1);
  const int tid = threadIdx.x;

  const size_t rs   = 3 * DMODEL;
  const size_t base = ((size_t)(b * SEQ + c * CS)) * rs + (size_t)h * HD;

  {
    const int r  = tid >> 2;
    const int sg = (tid & 3) * 16;
    const ushort* src = qkvb + base + (size_t)r * rs + sg;
    ushort8 q0 = *(const ushort8*)(src);
    ushort8 q1 = *(const ushort8*)(src + 8);
    ushort8 k0 = *(const ushort8*)(src + DMODEL);
    ushort8 k1 = *(const ushort8*)(src + DMODEL + 8);
    ushort8 v0 = *(const ushort8*)(src + 2 * DMODEL);
    ushort8 v1 = *(const ushort8*)(src + 2 * DMODEL + 8);
    *(ushort8*)&Qs[r * LP + sg]     = q0;
    *(ushort8*)&Qs[r * LP + sg + 8] = q1;
    *(ushort8*)&Ks[r * LP + sg]     = k0;
    *(ushort8*)&Ks[r * LP + sg + 8] = k1;
    #pragma unroll
    for (int j = 0; j < 8; ++j) {
      Vt[(sg + j) * LP + r]     = v0[j];
      Vt[(sg + 8 + j) * LP + r] = v1[j];
    }
  }
  // Vt rows 64..79: row 64 = 1.0, rest 0
  {
    const int idx = tid * 4;                 // 0..1023
    const int row = 64 + (idx >> 6);
    const int col = idx & 63;
    const ushort val = (row == 64) ? (ushort)0x3F80 : (ushort)0;
    ushort4 v4 = {val, val, val, val};
    *(ushort4*)&Vt[row * LP + col] = v4;
  }
  // Kv rows 0..63 direct bf16 copy; row 64 = ksum; rows 65..79 = 0
  {
    const ushort* sp = state + ((size_t)bh * NC + c) * STSZ;
    const int off = tid * 16;                // 0..4095
    const int e   = off >> 6;
    const int col = off & 63;
    *(ushort8*)&Kv[e * LP + col]     = *(const ushort8*)(sp + off);
    *(ushort8*)&Kv[e * LP + col + 8] = *(const ushort8*)(sp + off + 8);
    if (tid < 16) {
      const int c4 = tid * 4;
      *(ushort4*)&Kv[64 * LP + c4] = *(const ushort4*)(sp + HD * HD + c4);
    }
    if (tid < 240) {
      const int idx = tid * 4;               // 0..959
      const int row = 65 + (idx >> 6);
      const int col2 = idx & 63;
      ushort4 z = {0, 0, 0, 0};
      *(ushort4*)&Kv[row * LP + col2] = z;
    }
  }
  __syncthreads();

  const int lane = tid & 63;
  const int w    = tid >> 6;
  const int l15  = lane & 15;
  const int khi  = (lane >> 4) * 8;

  // ---- S = Q K^T for row stripe w*16..w*16+15 ----
  bf16x8 qa[2];
  #pragma unroll
  for (int kk = 0; kk < 2; ++kk)
    qa[kk] = *(const bf16x8*)&Qs[(w * 16 + l15) * LP + kk * 32 + khi];

  {
    f32x4 sac[4];
    #pragma unroll
    for (int ct = 0; ct < 4; ++ct) {
      sac[ct] = (f32x4)0.f;
      #pragma unroll
      for (int kk = 0; kk < 2; ++kk)
        sac[ct] = __builtin_amdgcn_mfma_f32_16x16x32_bf16(
            qa[kk], *(const bf16x8*)&Ks[(ct * 16 + l15) * LP + kk * 32 + khi],
            sac[ct], 0, 0, 0);
    }
    const int t0 = w * 16 + (lane >> 4) * 4;
    #pragma unroll
    for (int ct = 0; ct < 4; ++ct) {
      const int s = ct * 16 + l15;
      #pragma unroll
      for (int i = 0; i < 4; ++i) {
        const int t = t0 + i;
        const float v = (s <= t) ? sac[ct][i] : 0.f;
        Sm[t * LP + s] = f2bf(v);
      }
    }
  }
  __syncthreads();

  // ---- O = Q @ KvAug + Sm @ VtAug  (N = 80) ----
  bf16x8 sa[2];
  #pragma unroll
  for (int kk = 0; kk < 2; ++kk)
    sa[kk] = *(const bf16x8*)&Sm[(w * 16 + l15) * LP + kk * 32 + khi];

  f32x4 o[5];
  #pragma unroll
  for (int ct = 0; ct < 5; ++ct) {
    o[ct] = (f32x4)0.f;
    #pragma unroll
    for (int kk = 0; kk < 2; ++kk)
      o[ct] = __builtin_amdgcn_mfma_f32_16x16x32_bf16(
          qa[kk], *(const bf16x8*)&Kv[(ct * 16 + l15) * LP + kk * 32 + khi],
          o[ct], 0, 0, 0);
    #pragma unroll
    for (int kk = 0; kk < 2; ++kk)
      o[ct] = __builtin_amdgcn_mfma_f32_16x16x32_bf16(
          sa[kk], *(const bf16x8*)&Vt[(ct * 16 + l15) * LP + kk * 32 + khi],
          o[ct], 0, 0, 0);
  }

  // ---- epilogue: den broadcast within 16-lane group, write y ----
  float den[4];
  #pragma unroll
  for (int i = 0; i < 4; ++i)
    den[i] = __shfl(o[4][i], lane & 48) + EPS_LA;

  const int t0 = w * 16 + (lane >> 4) * 4;
  #pragma unroll
  for (int ct = 0; ct < 4; ++ct) {
    const int e = ct * 16 + l15;
    #pragma unroll
    for (int i = 0; i < 4; ++i) {
      const int t = t0 + i;
      y[((size_t)(b * SEQ + c * CS + t)) * DMODEL + (size_t)h * HD + e] =
          f2bf(o[ct][i] / den[i]);
    }
  }
}

// ---------------------------------------------------------------------------
extern "C" void kernel_launch(void* const* d_in, const int* in_sizes, int n_in,
                              void* d_out, int out_size, void* d_ws,
                              size_t ws_size, hipStream_t stream) {
  (void)in_sizes; (void)n_in; (void)out_size; (void)ws_size;
  const float* x    = (const float*)d_in[0];
  const float* wqkv = (const float*)d_in[1];
  const float* wo   = (const float*)d_in[2];
  float* out = (float*)d_out;

  const int M  = 2 * SEQ;     // 4096
  const int K  = DMODEL;      // 1024
  const int N1 = 3 * DMODEL;  // 3072
  const int N2 = DMODEL;      // 1024

  // workspace layout (~56 MiB)
  ushort* stateb = (ushort*)d_ws;                           // 8.125 MiB
  ushort* qkvb   = stateb + (size_t)2 * NHEADS * NC * STSZ; // 24 MiB
  ushort* xb     = qkvb + (size_t)M * N1;                   // 8 MiB
  ushort* yb     = xb + (size_t)M * K;                      // 8 MiB
  ushort* wqkvT  = yb + (size_t)M * K;                      // 6 MiB
  ushort* woT    = wqkvT + (size_t)K * N1;                  // 2 MiB

  dim3 blk(256);

  prep<<<dim3(4096 + 768 + 256), blk, 0, stream>>>(x, wqkv, wo, xb, wqkvT, woT);

  gemm_ph<true><<<dim3((N1 / 128) * (M / 128)), blk, 0, stream>>>(
      xb, wqkvT, qkvb, M, N1, K, 2 * DMODEL, N1 / 128);

  chunk_sums_mfma<<<dim3(2 * NHEADS * NC), blk, 0, stream>>>(qkvb, stateb);

  const int total = 2 * NHEADS * STSZ;
  chunk_prefix<<<dim3((total + 255) / 256), blk, 0, stream>>>(stateb);

  chunk_out_mfma<<<dim3(2 * NHEADS * NC), blk, 0, stream>>>(qkvb, stateb, yb);

  gemm_ph<false><<<dim3((N2 / 128) * (M / 128)), blk, 0, stream>>>(
      yb, woT, out, M, N2, K, 0, N2 / 128);
}